// Round 1
// baseline (392.019 us; speedup 1.0000x reference)
//
#include <hip/hip_runtime.h>

#define B_  64
#define T_  1000
#define DV_ 512
#define DQ_ 1024
#define U_  128
#define F_  32
#define KS_ 31

typedef __attribute__((ext_vector_type(8))) short short8;
typedef __attribute__((ext_vector_type(4))) float f32x4;

// round-to-nearest-even f32 -> bf16 (bit trick), packed pair
__device__ __forceinline__ unsigned pk2(float a, float b) {
    union { float f; unsigned u; } x, y;
    x.f = a; y.f = b;
    unsigned ra = (x.u + 0x7FFFu + ((x.u >> 16) & 1u)) >> 16;
    unsigned rb = (y.u + 0x7FFFu + ((y.u >> 16) & 1u)) >> 16;
    return (ra & 0xFFFFu) | (rb << 16);
}

__device__ __forceinline__ float fast_tanh(float x) {
    // tanh(x) = 1 - 2/(e^{2x}+1); exp overflow -> +inf -> 1.0 (correct limit)
    return 1.0f - 2.0f / (__expf(2.0f * x) + 1.0f);
}

// ---------------------------------------------------------------------------
// Repack Wm [512,128] and Wl [32,128] into bf16, B-fragment layout:
// entry e = n*4 + koct (n = out col, koct = k-octet within 32-wide k-chunk),
// 8 bf16 per entry = k ascending. WmX has 16 such 8KB chunks (one per kc).
// ---------------------------------------------------------------------------
__global__ void prep_kernel(const float* __restrict__ Wm, const float* __restrict__ Wl,
                            short* __restrict__ WmX, short* __restrict__ WlX) {
    int g = blockIdx.x * 256 + threadIdx.x;
    if (g < 8192) {
        int kc = g >> 9, e = g & 511;
        int n = e >> 2, q = e & 3;
        int kb = kc * 32 + q * 8;
        int4 p;
        p.x = pk2(Wm[(kb + 0) * U_ + n], Wm[(kb + 1) * U_ + n]);
        p.y = pk2(Wm[(kb + 2) * U_ + n], Wm[(kb + 3) * U_ + n]);
        p.z = pk2(Wm[(kb + 4) * U_ + n], Wm[(kb + 5) * U_ + n]);
        p.w = pk2(Wm[(kb + 6) * U_ + n], Wm[(kb + 7) * U_ + n]);
        ((int4*)WmX)[g] = p;
    } else if (g < 8704) {
        int e = g - 8192;
        int n = e >> 2, q = e & 3;
        int kb = q * 8;   // only 32 k values
        int4 p;
        p.x = pk2(Wl[(kb + 0) * U_ + n], Wl[(kb + 1) * U_ + n]);
        p.y = pk2(Wl[(kb + 2) * U_ + n], Wl[(kb + 3) * U_ + n]);
        p.z = pk2(Wl[(kb + 4) * U_ + n], Wl[(kb + 5) * U_ + n]);
        p.w = pk2(Wl[(kb + 6) * U_ + n], Wl[(kb + 7) * U_ + n]);
        ((int4*)WlX)[e] = p;
    }
}

// ---------------------------------------------------------------------------
// qb[b,u] = query[b,:] @ Wq[:,u] + bq[u] + bm[u]   (bm folded in)
// ---------------------------------------------------------------------------
__global__ void qb_kernel(const float* __restrict__ query, const float* __restrict__ Wq,
                          const float* __restrict__ bq, const float* __restrict__ bm,
                          float* __restrict__ qb) {
    __shared__ float qs[DQ_];
    int b = blockIdx.x, tid = threadIdx.x;
#pragma unroll
    for (int i = 0; i < 8; ++i) qs[tid + i * 128] = query[b * DQ_ + tid + i * 128];
    __syncthreads();
    float a = 0.f;
#pragma unroll 8
    for (int k = 0; k < DQ_; ++k) a += qs[k] * Wq[k * U_ + tid];
    qb[b * U_ + tid] = a + bq[tid] + bm[tid];
}

// ---------------------------------------------------------------------------
// scores[r] for r = b*T+t: tanh(values@Wm + qb + tanh(conv(prev)@Wl)) @ Wv + bv
// 64-row tile per block, full 128 cols, bf16 MFMA 16x16x32.
// ---------------------------------------------------------------------------
__global__ __launch_bounds__(256) void score_kernel(
    const float* __restrict__ values, const float* __restrict__ prev,
    const float* __restrict__ Wc, const float* __restrict__ Wv,
    const float* __restrict__ bv, const short* __restrict__ WmX,
    const short* __restrict__ WlX, const float* __restrict__ qb,
    float* __restrict__ scores)
{
    __shared__ short As[2048];    // A tile: entry (row*4+koct), 8 bf16 each
    __shared__ short Bs[4096];    // B tile: entry (col*4+koct)
    __shared__ short AsL[2048];   // loc_pre tile (K=32)
    __shared__ short BsL[4096];   // Wl bf16 (staged once)
    __shared__ float WcS[KS_ * F_];
    __shared__ float qbS[2 * U_];
    __shared__ float WvS[U_];

    int tid = threadIdx.x;
    int r0 = blockIdx.x * 64;
    int b0 = r0 / T_;
    int b1 = (r0 + 63) / T_;

    // one-time stages (covered by first in-loop barrier)
    for (int i = tid; i < KS_ * F_; i += 256) WcS[i] = Wc[i];
    if (tid < U_) WvS[tid] = Wv[tid];
    {
        int bb = (tid < U_) ? b0 : b1;
        qbS[tid] = qb[bb * U_ + (tid & (U_ - 1))];
    }
    {
        const int4* src = (const int4*)WlX;
        int4* dst = (int4*)BsL;
        dst[tid] = src[tid];
        dst[tid + 256] = src[tid + 256];
    }

    f32x4 acc[8] = {};

    int wv   = tid >> 6;
    int lane = tid & 63;
    int quad = lane >> 4;
    int m15  = lane & 15;
    int afIdx = (wv * 16 + m15) * 4 + quad;

    // staging assignment: 4 consecutive threads cover one row's 32-float chunk
    int si = tid >> 2, sq = tid & 3;
    const float* aG = values + (size_t)(r0 + si) * DV_ + sq * 8;
    int4* asDst = ((int4*)As) + (si * 4 + sq);

    for (int kc = 0; kc < 16; ++kc) {
        float4 f0 = *(const float4*)(aG + kc * 32);
        float4 f1 = *(const float4*)(aG + kc * 32 + 4);
        int4 p;
        p.x = pk2(f0.x, f0.y); p.y = pk2(f0.z, f0.w);
        p.z = pk2(f1.x, f1.y); p.w = pk2(f1.z, f1.w);
        *asDst = p;
        const int4* bsrc = ((const int4*)WmX) + kc * 512;
        int4* bdst = (int4*)Bs;
        bdst[tid] = bsrc[tid];
        bdst[tid + 256] = bsrc[tid + 256];
        __syncthreads();
        short8 af = ((const short8*)As)[afIdx];
#pragma unroll
        for (int c = 0; c < 8; ++c) {
            short8 bf = ((const short8*)Bs)[(c * 16 + m15) * 4 + quad];
            acc[c] = __builtin_amdgcn_mfma_f32_16x16x32_bf16(af, bf, acc[c], 0, 0, 0);
        }
        __syncthreads();
    }

    // location conv: loc_pre[i,f] = sum_k prev[b, t+k-15] * Wc[k,f]  (SAME pad)
    {
        int i = tid & 63, fg = tid >> 6;
        int r = r0 + i;
        int b = r / T_;
        int t = r - b * T_;
        const float* pv = prev + b * T_;
        float a8[8] = {};
#pragma unroll
        for (int k = 0; k < KS_; ++k) {
            int tt = t + k - 15;
            float p = ((unsigned)tt < (unsigned)T_) ? pv[tt] : 0.f;
#pragma unroll
            for (int j = 0; j < 8; ++j) a8[j] += p * WcS[k * F_ + fg * 8 + j];
        }
        int4 pq;
        pq.x = pk2(a8[0], a8[1]); pq.y = pk2(a8[2], a8[3]);
        pq.z = pk2(a8[4], a8[5]); pq.w = pk2(a8[6], a8[7]);
        ((int4*)AsL)[i * 4 + fg] = pq;
    }
    __syncthreads();

    // loc GEMM (K=32, one MFMA per col chunk) into a SEPARATE accumulator:
    // reference applies tanh to loc before the sum.
    f32x4 lacc[8] = {};
    {
        short8 af = ((const short8*)AsL)[afIdx];
#pragma unroll
        for (int c = 0; c < 8; ++c) {
            short8 bf = ((const short8*)BsL)[(c * 16 + m15) * 4 + quad];
            lacc[c] = __builtin_amdgcn_mfma_f32_16x16x32_bf16(af, bf, lacc[c], 0, 0, 0);
        }
    }

    // epilogue: h = m + q + tanh(locU); score = sum_col tanh(h)*Wv[col] + bv
    float psum[4] = {0.f, 0.f, 0.f, 0.f};
    int qoff[4];
#pragma unroll
    for (int v = 0; v < 4; ++v) {
        int r = r0 + wv * 16 + quad * 4 + v;
        qoff[v] = ((r / T_) == b0) ? 0 : U_;
    }
#pragma unroll
    for (int c = 0; c < 8; ++c) {
        int col = c * 16 + m15;
        float wvv = WvS[col];
#pragma unroll
        for (int v = 0; v < 4; ++v) {
            float tl = fast_tanh(lacc[c][v]);
            float h = acc[c][v] + qbS[qoff[v] + col] + tl;
            psum[v] += fast_tanh(h) * wvv;
        }
    }
#pragma unroll
    for (int off = 1; off < 16; off <<= 1) {
#pragma unroll
        for (int v = 0; v < 4; ++v) psum[v] += __shfl_xor(psum[v], off);
    }
    if (m15 == 0) {
        float bvv = bv[0];
#pragma unroll
        for (int v = 0; v < 4; ++v)
            scores[r0 + wv * 16 + quad * 4 + v] = psum[v] + bvv;
    }
}

// ---------------------------------------------------------------------------
// softmax over time per batch row; weights written straight into d_out.
// ---------------------------------------------------------------------------
__global__ void softmax_kernel(const float* __restrict__ s, float* __restrict__ w) {
    __shared__ float red[4];
    int b = blockIdx.x, tid = threadIdx.x;
    const float* sb = s + b * T_;
    float v[4];
    int tv[4];
#pragma unroll
    for (int i = 0; i < 4; ++i) {
        int t = tid + i * 256;
        tv[i] = t;
        v[i] = (t < T_) ? sb[t] : -1e30f;
    }
    float mx = fmaxf(fmaxf(v[0], v[1]), fmaxf(v[2], v[3]));
#pragma unroll
    for (int off = 32; off >= 1; off >>= 1) mx = fmaxf(mx, __shfl_xor(mx, off));
    int wv = tid >> 6, lane = tid & 63;
    if (lane == 0) red[wv] = mx;
    __syncthreads();
    mx = fmaxf(fmaxf(red[0], red[1]), fmaxf(red[2], red[3]));
    float e[4];
    float sum = 0.f;
#pragma unroll
    for (int i = 0; i < 4; ++i) {
        e[i] = (tv[i] < T_) ? __expf(v[i] - mx) : 0.f;
        sum += e[i];
    }
#pragma unroll
    for (int off = 32; off >= 1; off >>= 1) sum += __shfl_xor(sum, off);
    __syncthreads();
    if (lane == 0) red[wv] = sum;
    __syncthreads();
    sum = red[0] + red[1] + red[2] + red[3];
    float inv = 1.0f / sum;
#pragma unroll
    for (int i = 0; i < 4; ++i)
        if (tv[i] < T_) w[b * T_ + tv[i]] = e[i] * inv;
}

// ---------------------------------------------------------------------------
// context[b,d] = sum_t w[b,t] * values[b,t,d]
// grid (64,4): block = (b, 128-col chunk), 2-way t-split inside block.
// ---------------------------------------------------------------------------
__global__ __launch_bounds__(256) void context_kernel(
    const float* __restrict__ values, const float* __restrict__ w,
    float* __restrict__ ctx)
{
    __shared__ float wS[T_];
    __shared__ float ps[128];
    int b = blockIdx.x;
    int cb = blockIdx.y * 128;
    int tid = threadIdx.x;
    for (int i = tid; i < T_; i += 256) wS[i] = w[b * T_ + i];
    __syncthreads();
    int cl = tid & 127, tp = tid >> 7;
    const float* vp = values + (size_t)b * T_ * DV_ + cb + cl + (size_t)tp * 500 * DV_;
    float acc = 0.f;
#pragma unroll 4
    for (int t = 0; t < 500; ++t)
        acc += wS[tp * 500 + t] * vp[(size_t)t * DV_];
    if (tp == 0) ps[cl] = acc;
    __syncthreads();
    if (tp == 1) ctx[b * DV_ + cb + cl] = ps[cl] + acc;
}

extern "C" void kernel_launch(void* const* d_in, const int* in_sizes, int n_in,
                              void* d_out, int out_size, void* d_ws, size_t ws_size,
                              hipStream_t stream) {
    const float* query  = (const float*)d_in[0];
    const float* values = (const float*)d_in[1];
    const float* prev   = (const float*)d_in[2];
    const float* Wq     = (const float*)d_in[3];
    const float* bq     = (const float*)d_in[4];
    const float* Wm     = (const float*)d_in[5];
    const float* bm     = (const float*)d_in[6];
    const float* Wv     = (const float*)d_in[7];
    const float* bv     = (const float*)d_in[8];
    const float* Wc     = (const float*)d_in[9];
    const float* Wl     = (const float*)d_in[10];

    float* out  = (float*)d_out;
    float* ctx  = out;                 // [64,512]
    float* attw = out + B_ * DV_;      // [64,1000,1]

    char* ws = (char*)d_ws;
    float* qb     = (float*)(ws);                              // 32768 B
    float* scores = (float*)(ws + 32768);                      // 256000 B
    short* WmX    = (short*)(ws + 32768 + 256000);             // 131072 B
    short* WlX    = (short*)(ws + 32768 + 256000 + 131072);    // 8192 B

    prep_kernel<<<34, 256, 0, stream>>>(Wm, Wl, WmX, WlX);
    qb_kernel<<<B_, 128, 0, stream>>>(query, Wq, bq, bm, qb);
    score_kernel<<<1000, 256, 0, stream>>>(values, prev, Wc, Wv, bv, WmX, WlX, qb, scores);
    softmax_kernel<<<B_, 256, 0, stream>>>(scores, attw);
    context_kernel<<<dim3(B_, 4), 256, 0, stream>>>(values, attw, ctx);
}

// Round 2
// 273.561 us; speedup vs baseline: 1.4330x; 1.4330x over previous
//
#include <hip/hip_runtime.h>

#define B_  64
#define T_  1000
#define DV_ 512
#define DQ_ 1024
#define U_  128
#define F_  32
#define KS_ 31
#define P_  8      // context partial count

typedef __attribute__((ext_vector_type(8))) short short8;
typedef __attribute__((ext_vector_type(4))) float f32x4;

// round-to-nearest-even f32 -> bf16 (bit trick), packed pair
__device__ __forceinline__ unsigned pk2(float a, float b) {
    union { float f; unsigned u; } x, y;
    x.f = a; y.f = b;
    unsigned ra = (x.u + 0x7FFFu + ((x.u >> 16) & 1u)) >> 16;
    unsigned rb = (y.u + 0x7FFFu + ((y.u >> 16) & 1u)) >> 16;
    return (ra & 0xFFFFu) | (rb << 16);
}

__device__ __forceinline__ float fast_tanh(float x) {
    return 1.0f - 2.0f / (__expf(2.0f * x) + 1.0f);
}

// load 8 consecutive floats at p, pack to bf16 short8 (k ascending)
__device__ __forceinline__ short8 loadA8(const float* __restrict__ p) {
    float4 f0 = *(const float4*)p;
    float4 f1 = *(const float4*)(p + 4);
    int4 q;
    q.x = pk2(f0.x, f0.y); q.y = pk2(f0.z, f0.w);
    q.z = pk2(f1.x, f1.y); q.w = pk2(f1.z, f1.w);
    return *(short8*)&q;
}

// ---------------------------------------------------------------------------
// Repack Wm [512,128] and Wl [32,128] into bf16 B-fragment layout:
// entry e = n*4 + koct within each 32-wide k chunk; 8 bf16 per entry.
// ---------------------------------------------------------------------------
__global__ void prep_kernel(const float* __restrict__ Wm, const float* __restrict__ Wl,
                            short* __restrict__ WmX, short* __restrict__ WlX) {
    int g = blockIdx.x * 256 + threadIdx.x;
    if (g < 8192) {
        int kc = g >> 9, e = g & 511;
        int n = e >> 2, q = e & 3;
        int kb = kc * 32 + q * 8;
        int4 p;
        p.x = pk2(Wm[(kb + 0) * U_ + n], Wm[(kb + 1) * U_ + n]);
        p.y = pk2(Wm[(kb + 2) * U_ + n], Wm[(kb + 3) * U_ + n]);
        p.z = pk2(Wm[(kb + 4) * U_ + n], Wm[(kb + 5) * U_ + n]);
        p.w = pk2(Wm[(kb + 6) * U_ + n], Wm[(kb + 7) * U_ + n]);
        ((int4*)WmX)[g] = p;
    } else if (g < 8704) {
        int e = g - 8192;
        int n = e >> 2, q = e & 3;
        int kb = q * 8;
        int4 p;
        p.x = pk2(Wl[(kb + 0) * U_ + n], Wl[(kb + 1) * U_ + n]);
        p.y = pk2(Wl[(kb + 2) * U_ + n], Wl[(kb + 3) * U_ + n]);
        p.z = pk2(Wl[(kb + 4) * U_ + n], Wl[(kb + 5) * U_ + n]);
        p.w = pk2(Wl[(kb + 6) * U_ + n], Wl[(kb + 7) * U_ + n]);
        ((int4*)WlX)[e] = p;
    }
}

// ---------------------------------------------------------------------------
// qb[b,u] = query[b,:] @ Wq[:,u] + bq[u] + bm[u]; 1024 threads, 8-way K split.
// ---------------------------------------------------------------------------
__global__ __launch_bounds__(1024) void qb_kernel(
    const float* __restrict__ query, const float* __restrict__ Wq,
    const float* __restrict__ bq, const float* __restrict__ bm,
    float* __restrict__ qb)
{
    __shared__ float qs[DQ_];
    __shared__ float red[8][U_];
    int b = blockIdx.x, tid = threadIdx.x;
    qs[tid] = query[b * DQ_ + tid];
    __syncthreads();
    int u = tid & 127, p = tid >> 7;
    float a = 0.f;
    const float* wp = Wq + (size_t)p * 128 * U_ + u;
    const float* qp = qs + p * 128;
#pragma unroll 8
    for (int k = 0; k < 128; ++k) a += qp[k] * wp[(size_t)k * U_];
    red[p][u] = a;
    __syncthreads();
    if (tid < U_) {
        float s = bq[tid] + bm[tid];
#pragma unroll
        for (int pp = 0; pp < 8; ++pp) s += red[pp][tid];
        qb[b * U_ + tid] = s;
    }
}

// ---------------------------------------------------------------------------
// scores[r], r=b*T+t: tanh(values@Wm + qb + tanh(conv(prev)@Wl)) @ Wv + bv
// 64 rows/block, barrier-free streaming main loop, A and B frags straight
// from global (A: coalesced 128B/row segments; B: L2-hot repacked WmX).
// ---------------------------------------------------------------------------
__global__ __launch_bounds__(256) void score_kernel(
    const float* __restrict__ values, const float* __restrict__ prev,
    const float* __restrict__ Wc, const float* __restrict__ Wv,
    const float* __restrict__ bv, const short* __restrict__ WmX,
    const short* __restrict__ WlX, const float* __restrict__ qb,
    float* __restrict__ scores)
{
    __shared__ float WcS[KS_ * F_];
    __shared__ short AsL[2048];        // conv result, A-frag layout + XOR swizzle
    __shared__ float qbS[2 * U_];
    __shared__ float WvS[U_];

    const int tid = threadIdx.x;
    const int r0 = blockIdx.x * 64;
    const int b0 = r0 / T_;
    const int b1 = (r0 + 63) / T_;

    for (int i = tid; i < KS_ * F_; i += 256) WcS[i] = Wc[i];
    if (tid < U_) WvS[tid] = Wv[tid];
    {
        int bb = (tid < U_) ? b0 : b1;
        qbS[tid] = qb[bb * U_ + (tid & (U_ - 1))];
    }

    const int wv = tid >> 6, lane = tid & 63;
    const int quad = lane >> 4, m15 = lane & 15;
    const int row = wv * 16 + m15;                       // A-row in tile
    const float* aP = values + (size_t)(r0 + row) * DV_ + quad * 8;
    const int4* bW  = (const int4*)WmX + m15 * 4 + quad;
    const int4* blW = (const int4*)WlX + m15 * 4 + quad;

    // prefetch kc=0 (stays in flight across barriers / conv)
    short8 afA, afB;
    int4 bfA[8], bfB[8];
    afA = loadA8(aP);
#pragma unroll
    for (int c = 0; c < 8; ++c) bfA[c] = bW[c * 64];

    __syncthreads();   // WcS / qbS / WvS ready

    // location conv: loc_pre[i,f] = sum_k prev[b, t+k-15]*Wc[k,f] (SAME pad)
    {
        int i = lane, fg = wv;           // i: row in tile, fg: 8-filter group
        int r = r0 + i;
        int b = r / T_;
        int t = r - b * T_;
        const float* pv = prev + b * T_;
        float a8[8] = {};
#pragma unroll
        for (int k = 0; k < KS_; ++k) {
            int tt = t + k - 15;
            float p = ((unsigned)tt < (unsigned)T_) ? pv[tt] : 0.f;
#pragma unroll
            for (int j = 0; j < 8; ++j) a8[j] += p * WcS[k * F_ + fg * 8 + j];
        }
        int4 pq;
        pq.x = pk2(a8[0], a8[1]); pq.y = pk2(a8[2], a8[3]);
        pq.z = pk2(a8[4], a8[5]); pq.w = pk2(a8[6], a8[7]);
        ((int4*)AsL)[i * 4 + (fg ^ ((i >> 1) & 3))] = pq;   // XOR swizzle
    }
    __syncthreads();

    // loc GEMM (K=32) -> acc init = qb + tanh(loc)
    f32x4 acc[8];
    {
        short8 afl = ((const short8*)AsL)[row * 4 + (quad ^ ((row >> 1) & 3))];
        f32x4 lacc[8] = {};
#pragma unroll
        for (int c = 0; c < 8; ++c) {
            int4 bl = blW[c * 64];
            lacc[c] = __builtin_amdgcn_mfma_f32_16x16x32_bf16(afl, *(short8*)&bl, lacc[c], 0, 0, 0);
        }
        int qoff[4];
#pragma unroll
        for (int v = 0; v < 4; ++v) {
            int r = r0 + wv * 16 + quad * 4 + v;
            qoff[v] = ((r / T_) == b0) ? 0 : U_;
        }
#pragma unroll
        for (int c = 0; c < 8; ++c) {
            int col = c * 16 + m15;
#pragma unroll
            for (int v = 0; v < 4; ++v)
                acc[c][v] = qbS[qoff[v] + col] + fast_tanh(lacc[c][v]);
        }
    }

    // barrier-free double-buffered main loop over 16 k-chunks
#pragma unroll
    for (int k2 = 0; k2 < 8; ++k2) {
        const int kc = k2 * 2;
        afB = loadA8(aP + (kc + 1) * 32);
#pragma unroll
        for (int c = 0; c < 8; ++c) bfB[c] = bW[(kc + 1) * 512 + c * 64];
#pragma unroll
        for (int c = 0; c < 8; ++c)
            acc[c] = __builtin_amdgcn_mfma_f32_16x16x32_bf16(afA, *(short8*)&bfA[c], acc[c], 0, 0, 0);
        if (kc + 2 < 16) {
            afA = loadA8(aP + (kc + 2) * 32);
#pragma unroll
            for (int c = 0; c < 8; ++c) bfA[c] = bW[(kc + 2) * 512 + c * 64];
        }
#pragma unroll
        for (int c = 0; c < 8; ++c)
            acc[c] = __builtin_amdgcn_mfma_f32_16x16x32_bf16(afB, *(short8*)&bfB[c], acc[c], 0, 0, 0);
    }

    // epilogue: score = sum_col tanh(acc)*Wv[col] + bv
    float psum[4] = {0.f, 0.f, 0.f, 0.f};
#pragma unroll
    for (int c = 0; c < 8; ++c) {
        int col = c * 16 + m15;
        float wvv = WvS[col];
#pragma unroll
        for (int v = 0; v < 4; ++v)
            psum[v] += fast_tanh(acc[c][v]) * wvv;
    }
#pragma unroll
    for (int off = 1; off < 16; off <<= 1) {
#pragma unroll
        for (int v = 0; v < 4; ++v) psum[v] += __shfl_xor(psum[v], off);
    }
    if (m15 == 0) {
        float bvv = bv[0];
#pragma unroll
        for (int v = 0; v < 4; ++v)
            scores[r0 + wv * 16 + quad * 4 + v] = psum[v] + bvv;
    }
}

// ---------------------------------------------------------------------------
// softmax over time per batch row; weights straight into d_out.
// ---------------------------------------------------------------------------
__global__ void softmax_kernel(const float* __restrict__ s, float* __restrict__ w) {
    __shared__ float red[4];
    int b = blockIdx.x, tid = threadIdx.x;
    const float* sb = s + b * T_;
    float v[4];
    int tv[4];
#pragma unroll
    for (int i = 0; i < 4; ++i) {
        int t = tid + i * 256;
        tv[i] = t;
        v[i] = (t < T_) ? sb[t] : -1e30f;
    }
    float mx = fmaxf(fmaxf(v[0], v[1]), fmaxf(v[2], v[3]));
#pragma unroll
    for (int off = 32; off >= 1; off >>= 1) mx = fmaxf(mx, __shfl_xor(mx, off));
    int wv = tid >> 6, lane = tid & 63;
    if (lane == 0) red[wv] = mx;
    __syncthreads();
    mx = fmaxf(fmaxf(red[0], red[1]), fmaxf(red[2], red[3]));
    float e[4];
    float sum = 0.f;
#pragma unroll
    for (int i = 0; i < 4; ++i) {
        e[i] = (tv[i] < T_) ? __expf(v[i] - mx) : 0.f;
        sum += e[i];
    }
#pragma unroll
    for (int off = 32; off >= 1; off >>= 1) sum += __shfl_xor(sum, off);
    __syncthreads();
    if (lane == 0) red[wv] = sum;
    __syncthreads();
    sum = red[0] + red[1] + red[2] + red[3];
    float inv = 1.0f / sum;
#pragma unroll
    for (int i = 0; i < 4; ++i)
        if (tv[i] < T_) w[b * T_ + tv[i]] = e[i] * inv;
}

// ---------------------------------------------------------------------------
// context phase 1: partial[b,p,d] = sum_{t in chunk p} w[b,t]*values[b,t,d]
// grid (64, P_=8), 125 t per chunk, float2 per thread (512 cols / 256 thr).
// ---------------------------------------------------------------------------
__global__ __launch_bounds__(256) void ctx1_kernel(
    const float* __restrict__ values, const float* __restrict__ w,
    float* __restrict__ part)
{
    __shared__ float wS[125];
    int b = blockIdx.x, p = blockIdx.y, tid = threadIdx.x;
    if (tid < 125) wS[tid] = w[b * T_ + p * 125 + tid];
    __syncthreads();
    const float* vp = values + ((size_t)b * T_ + p * 125) * DV_ + tid * 2;
    float ax = 0.f, ay = 0.f;
#pragma unroll 5
    for (int t = 0; t < 125; ++t) {
        float2 v = *(const float2*)(vp + (size_t)t * DV_);
        ax += wS[t] * v.x;
        ay += wS[t] * v.y;
    }
    float2 o; o.x = ax; o.y = ay;
    *(float2*)(part + ((size_t)(b * P_ + p)) * DV_ + tid * 2) = o;
}

// context phase 2: ctx[b,d] = sum_p partial[b,p,d]
__global__ void ctx2_kernel(const float* __restrict__ part, float* __restrict__ ctx) {
    int b = blockIdx.x, tid = threadIdx.x;
    float ax = 0.f, ay = 0.f;
    const float* pp = part + (size_t)b * P_ * DV_ + tid * 2;
#pragma unroll
    for (int p = 0; p < P_; ++p) {
        float2 v = *(const float2*)(pp + (size_t)p * DV_);
        ax += v.x; ay += v.y;
    }
    float2 o; o.x = ax; o.y = ay;
    *(float2*)(ctx + (size_t)b * DV_ + tid * 2) = o;
}

extern "C" void kernel_launch(void* const* d_in, const int* in_sizes, int n_in,
                              void* d_out, int out_size, void* d_ws, size_t ws_size,
                              hipStream_t stream) {
    const float* query  = (const float*)d_in[0];
    const float* values = (const float*)d_in[1];
    const float* prev   = (const float*)d_in[2];
    const float* Wq     = (const float*)d_in[3];
    const float* bq     = (const float*)d_in[4];
    const float* Wm     = (const float*)d_in[5];
    const float* bm     = (const float*)d_in[6];
    const float* Wv     = (const float*)d_in[7];
    const float* bv     = (const float*)d_in[8];
    const float* Wc     = (const float*)d_in[9];
    const float* Wl     = (const float*)d_in[10];

    float* out  = (float*)d_out;
    float* ctx  = out;                 // [64,512]
    float* attw = out + B_ * DV_;      // [64,1000,1]

    char* ws = (char*)d_ws;
    float* qb     = (float*)(ws);                              // 32768 B
    float* scores = (float*)(ws + 32768);                      // 256000 B
    short* WmX    = (short*)(ws + 32768 + 256000);             // 131072 B
    short* WlX    = (short*)(ws + 32768 + 256000 + 131072);    // 8192 B
    float* part   = (float*)(ws + 32768 + 256000 + 131072 + 8192); // 1 MB

    prep_kernel<<<34, 256, 0, stream>>>(Wm, Wl, WmX, WlX);
    qb_kernel<<<B_, 1024, 0, stream>>>(query, Wq, bq, bm, qb);
    score_kernel<<<1000, 256, 0, stream>>>(values, prev, Wc, Wv, bv, WmX, WlX, qb, scores);
    softmax_kernel<<<B_, 256, 0, stream>>>(scores, attw);
    ctx1_kernel<<<dim3(B_, P_), 256, 0, stream>>>(values, attw, part);
    ctx2_kernel<<<B_, 256, 0, stream>>>(part, ctx);
}

// Round 3
// 272.813 us; speedup vs baseline: 1.4369x; 1.0027x over previous
//
#include <hip/hip_runtime.h>

#define B_  64
#define T_  1000
#define DV_ 512
#define DQ_ 1024
#define U_  128
#define F_  32
#define KS_ 31
#define P_  16     // context partial chunks per batch
#define CT_ 63     // t per chunk (last chunk 55)

typedef __attribute__((ext_vector_type(8))) short short8;
typedef __attribute__((ext_vector_type(4))) float f32x4;

// round-to-nearest-even f32 -> bf16 (bit trick), packed pair
__device__ __forceinline__ unsigned pk2(float a, float b) {
    union { float f; unsigned u; } x, y;
    x.f = a; y.f = b;
    unsigned ra = (x.u + 0x7FFFu + ((x.u >> 16) & 1u)) >> 16;
    unsigned rb = (y.u + 0x7FFFu + ((y.u >> 16) & 1u)) >> 16;
    return (ra & 0xFFFFu) | (rb << 16);
}

__device__ __forceinline__ float fast_tanh(float x) {
    return 1.0f - 2.0f / (__expf(2.0f * x) + 1.0f);
}

// pack two float4 (8 consecutive k) into bf16 short8
__device__ __forceinline__ short8 pk8(float4 f0, float4 f1) {
    int4 q;
    q.x = pk2(f0.x, f0.y); q.y = pk2(f0.z, f0.w);
    q.z = pk2(f1.x, f1.y); q.w = pk2(f1.z, f1.w);
    return *(short8*)&q;
}

// ---------------------------------------------------------------------------
// Merged: prep (repack Wm/Wl to bf16 B-frag layout) + qb (query proj).
// Blocks 0..8: prep. Blocks 9..72: qb for b = blk-9.
// ---------------------------------------------------------------------------
__global__ __launch_bounds__(1024) void prep_qb_kernel(
    const float* __restrict__ Wm, const float* __restrict__ Wl,
    const float* __restrict__ query, const float* __restrict__ Wq,
    const float* __restrict__ bq, const float* __restrict__ bm,
    short* __restrict__ WmX, short* __restrict__ WlX, float* __restrict__ qb)
{
    __shared__ float sh[DQ_ + 8 * U_];
    int blk = blockIdx.x, tid = threadIdx.x;
    if (blk < 9) {
        int g = blk * 1024 + tid;
        if (g < 8192) {
            int kc = g >> 9, e = g & 511;
            int n = e >> 2, q = e & 3;
            int kb = kc * 32 + q * 8;
            int4 p;
            p.x = pk2(Wm[(kb + 0) * U_ + n], Wm[(kb + 1) * U_ + n]);
            p.y = pk2(Wm[(kb + 2) * U_ + n], Wm[(kb + 3) * U_ + n]);
            p.z = pk2(Wm[(kb + 4) * U_ + n], Wm[(kb + 5) * U_ + n]);
            p.w = pk2(Wm[(kb + 6) * U_ + n], Wm[(kb + 7) * U_ + n]);
            ((int4*)WmX)[g] = p;
        } else if (g < 8704) {
            int e = g - 8192;
            int n = e >> 2, q = e & 3;
            int kb = q * 8;
            int4 p;
            p.x = pk2(Wl[(kb + 0) * U_ + n], Wl[(kb + 1) * U_ + n]);
            p.y = pk2(Wl[(kb + 2) * U_ + n], Wl[(kb + 3) * U_ + n]);
            p.z = pk2(Wl[(kb + 4) * U_ + n], Wl[(kb + 5) * U_ + n]);
            p.w = pk2(Wl[(kb + 6) * U_ + n], Wl[(kb + 7) * U_ + n]);
            ((int4*)WlX)[e] = p;
        }
    } else {
        float* qs = sh;
        float* red = sh + DQ_;
        int b = blk - 9;
        qs[tid] = query[b * DQ_ + tid];
        __syncthreads();
        int u = tid & 127, p = tid >> 7;
        float a = 0.f;
        const float* wp = Wq + (size_t)p * 128 * U_ + u;
        const float* qp = qs + p * 128;
#pragma unroll 8
        for (int k = 0; k < 128; ++k) a += qp[k] * wp[(size_t)k * U_];
        red[p * U_ + u] = a;
        __syncthreads();
        if (tid < U_) {
            float s = bq[tid] + bm[tid];
#pragma unroll
            for (int pp = 0; pp < 8; ++pp) s += red[pp * U_ + tid];
            qb[b * U_ + tid] = s;
        }
    }
}

// ---------------------------------------------------------------------------
// scores[r], r=b*T+t: tanh(values@Wm + qb + tanh(conv(prev)@Wl)) @ Wv + bv
// 128 rows/block (500 blocks), 4 waves; each wave: 2 row-groups x 128 cols.
// Barrier-free streaming K-loop: A from global (dist-2 prefetch, HBM/L3),
// B from repacked WmX (dist-1, L2-hot), B-frags shared by both row groups.
// ---------------------------------------------------------------------------
__global__ __launch_bounds__(256) void score_kernel(
    const float* __restrict__ values, const float* __restrict__ prev,
    const float* __restrict__ Wc, const float* __restrict__ Wv,
    const float* __restrict__ bv, const short* __restrict__ WmX,
    const short* __restrict__ WlX, const float* __restrict__ qb,
    float* __restrict__ scores)
{
    __shared__ float WcS[KS_ * F_];
    __shared__ short AsL[128 * 32];    // conv result, A-frag layout + XOR swizzle
    __shared__ float qbS[2 * U_];
    __shared__ float WvS[U_];

    const int tid = threadIdx.x;
    const int r0 = blockIdx.x * 128;
    const int b0 = r0 / T_;
    const int b1 = (r0 + 127) / T_;

    for (int i = tid; i < KS_ * F_; i += 256) WcS[i] = Wc[i];
    if (tid < U_) WvS[tid] = Wv[tid];
    {
        int bb = (tid < U_) ? b0 : b1;
        qbS[tid] = qb[bb * U_ + (tid & (U_ - 1))];
    }

    const int wv = tid >> 6, lane = tid & 63;
    const int quad = lane >> 4, m15 = lane & 15;
    const int row0 = wv * 32 + m15;          // row-group 0 row in tile
    const float* aP0 = values + (size_t)(r0 + row0) * DV_ + quad * 8;
    const float* aP1 = aP0 + (size_t)16 * DV_;
    const int4* bW  = (const int4*)WmX + m15 * 4 + quad;
    const int4* blW = (const int4*)WlX + m15 * 4 + quad;

    // prefetch: A for kc=0,1 ; B for kc=0 (stay in flight across conv/barriers)
    float4 aq0[2][2], aq1[2][2], aq2[2][2];
    int4 bf0[8], bf1[8];
    aq0[0][0] = *(const float4*)(aP0);      aq0[0][1] = *(const float4*)(aP0 + 4);
    aq0[1][0] = *(const float4*)(aP1);      aq0[1][1] = *(const float4*)(aP1 + 4);
    aq1[0][0] = *(const float4*)(aP0 + 32); aq1[0][1] = *(const float4*)(aP0 + 36);
    aq1[1][0] = *(const float4*)(aP1 + 32); aq1[1][1] = *(const float4*)(aP1 + 36);
#pragma unroll
    for (int c = 0; c < 8; ++c) bf0[c] = bW[c * 64];

    __syncthreads();   // WcS / qbS / WvS ready

    // location conv: loc_pre[i,f] = sum_k prev[b, t+k-15]*Wc[k,f] (SAME pad)
    // 512 (row, 8-filter-group) items, 2 per thread.
#pragma unroll
    for (int it = 0; it < 2; ++it) {
        int idx = tid + it * 256;
        int i = idx & 127, fg = idx >> 7;
        int r = r0 + i;
        int b = r / T_;
        int t = r - b * T_;
        const float* pv = prev + b * T_;
        float a8[8] = {};
#pragma unroll
        for (int k = 0; k < KS_; ++k) {
            int tt = t + k - 15;
            float p = ((unsigned)tt < (unsigned)T_) ? pv[tt] : 0.f;
#pragma unroll
            for (int j = 0; j < 8; ++j) a8[j] += p * WcS[k * F_ + fg * 8 + j];
        }
        int4 pq;
        pq.x = pk2(a8[0], a8[1]); pq.y = pk2(a8[2], a8[3]);
        pq.z = pk2(a8[4], a8[5]); pq.w = pk2(a8[6], a8[7]);
        ((int4*)AsL)[i * 4 + (fg ^ ((i >> 1) & 3))] = pq;   // XOR swizzle
    }
    __syncthreads();

    // loc GEMM (K=32) into acc, then acc = qb + tanh(acc)
    f32x4 acc[2][8] = {};
    {
        int row1 = row0 + 16;
        short8 afl0 = ((const short8*)AsL)[row0 * 4 + (quad ^ ((row0 >> 1) & 3))];
        short8 afl1 = ((const short8*)AsL)[row1 * 4 + (quad ^ ((row1 >> 1) & 3))];
#pragma unroll
        for (int c = 0; c < 8; ++c) {
            int4 bl = blW[c * 64];
            acc[0][c] = __builtin_amdgcn_mfma_f32_16x16x32_bf16(afl0, *(short8*)&bl, acc[0][c], 0, 0, 0);
            acc[1][c] = __builtin_amdgcn_mfma_f32_16x16x32_bf16(afl1, *(short8*)&bl, acc[1][c], 0, 0, 0);
        }
        int qoff[2][4];
#pragma unroll
        for (int g = 0; g < 2; ++g)
#pragma unroll
            for (int v = 0; v < 4; ++v) {
                int r = r0 + wv * 32 + g * 16 + quad * 4 + v;
                qoff[g][v] = ((r / T_) == b0) ? 0 : U_;
            }
#pragma unroll
        for (int g = 0; g < 2; ++g)
#pragma unroll
            for (int c = 0; c < 8; ++c) {
                int col = c * 16 + m15;
#pragma unroll
                for (int v = 0; v < 4; ++v)
                    acc[g][c][v] = qbS[qoff[g][v] + col] + fast_tanh(acc[g][c][v]);
            }
    }

    // barrier-free streaming main loop (A dist-2, B dist-1, full unroll)
#pragma unroll
    for (int kc = 0; kc < 16; ++kc) {
        if (kc + 2 < 16) {
            aq2[0][0] = *(const float4*)(aP0 + (kc + 2) * 32);
            aq2[0][1] = *(const float4*)(aP0 + (kc + 2) * 32 + 4);
            aq2[1][0] = *(const float4*)(aP1 + (kc + 2) * 32);
            aq2[1][1] = *(const float4*)(aP1 + (kc + 2) * 32 + 4);
        }
        if (kc + 1 < 16) {
#pragma unroll
            for (int c = 0; c < 8; ++c) bf1[c] = bW[(kc + 1) * 512 + c * 64];
        }
        short8 af0 = pk8(aq0[0][0], aq0[0][1]);
        short8 af1 = pk8(aq0[1][0], aq0[1][1]);
#pragma unroll
        for (int c = 0; c < 8; ++c) {
            acc[0][c] = __builtin_amdgcn_mfma_f32_16x16x32_bf16(af0, *(short8*)&bf0[c], acc[0][c], 0, 0, 0);
            acc[1][c] = __builtin_amdgcn_mfma_f32_16x16x32_bf16(af1, *(short8*)&bf0[c], acc[1][c], 0, 0, 0);
        }
        // rotate queues (renamed away by full unroll)
#pragma unroll
        for (int g = 0; g < 2; ++g) {
            aq0[g][0] = aq1[g][0]; aq0[g][1] = aq1[g][1];
            aq1[g][0] = aq2[g][0]; aq1[g][1] = aq2[g][1];
        }
#pragma unroll
        for (int c = 0; c < 8; ++c) bf0[c] = bf1[c];
    }

    // epilogue: score = sum_col tanh(acc)*Wv[col] + bv
    float psum[2][4] = {};
#pragma unroll
    for (int g = 0; g < 2; ++g)
#pragma unroll
        for (int c = 0; c < 8; ++c) {
            int col = c * 16 + m15;
            float wvv = WvS[col];
#pragma unroll
            for (int v = 0; v < 4; ++v)
                psum[g][v] += fast_tanh(acc[g][c][v]) * wvv;
        }
#pragma unroll
    for (int off = 1; off < 16; off <<= 1) {
#pragma unroll
        for (int g = 0; g < 2; ++g)
#pragma unroll
            for (int v = 0; v < 4; ++v) psum[g][v] += __shfl_xor(psum[g][v], off);
    }
    if (m15 == 0) {
        float bvv = bv[0];
#pragma unroll
        for (int g = 0; g < 2; ++g)
#pragma unroll
            for (int v = 0; v < 4; ++v)
                scores[r0 + wv * 32 + g * 16 + quad * 4 + v] = psum[g][v] + bvv;
    }
}

// ---------------------------------------------------------------------------
// softmax over time per batch row; weights straight into d_out.
// ---------------------------------------------------------------------------
__global__ void softmax_kernel(const float* __restrict__ s, float* __restrict__ w) {
    __shared__ float red[4];
    int b = blockIdx.x, tid = threadIdx.x;
    const float* sb = s + b * T_;
    float v[4];
    int tv[4];
#pragma unroll
    for (int i = 0; i < 4; ++i) {
        int t = tid + i * 256;
        tv[i] = t;
        v[i] = (t < T_) ? sb[t] : -1e30f;
    }
    float mx = fmaxf(fmaxf(v[0], v[1]), fmaxf(v[2], v[3]));
#pragma unroll
    for (int off = 32; off >= 1; off >>= 1) mx = fmaxf(mx, __shfl_xor(mx, off));
    int wv = tid >> 6, lane = tid & 63;
    if (lane == 0) red[wv] = mx;
    __syncthreads();
    mx = fmaxf(fmaxf(red[0], red[1]), fmaxf(red[2], red[3]));
    float e[4];
    float sum = 0.f;
#pragma unroll
    for (int i = 0; i < 4; ++i) {
        e[i] = (tv[i] < T_) ? __expf(v[i] - mx) : 0.f;
        sum += e[i];
    }
#pragma unroll
    for (int off = 32; off >= 1; off >>= 1) sum += __shfl_xor(sum, off);
    __syncthreads();
    if (lane == 0) red[wv] = sum;
    __syncthreads();
    sum = red[0] + red[1] + red[2] + red[3];
    float inv = 1.0f / sum;
#pragma unroll
    for (int i = 0; i < 4; ++i)
        if (tv[i] < T_) w[b * T_ + tv[i]] = e[i] * inv;
}

// ---------------------------------------------------------------------------
// context phase 1: partial[b,p,d] = sum_{t in chunk p} w[b,t]*values[b,t,d]
// grid (64, 16): chunk 63 t (last 55); 256 thr: 128 col-groups (float4) x
// 2-way t split + LDS pair-reduce.
// ---------------------------------------------------------------------------
__global__ __launch_bounds__(256) void ctx1_kernel(
    const float* __restrict__ values, const float* __restrict__ w,
    float* __restrict__ part)
{
    __shared__ float wS[CT_];
    __shared__ float4 ps[128];
    int b = blockIdx.x, p = blockIdx.y, tid = threadIdx.x;
    int t0 = p * CT_;
    int len = (T_ - t0 < CT_) ? (T_ - t0) : CT_;
    if (tid < len) wS[tid] = w[b * T_ + t0 + tid];
    __syncthreads();
    int cl = tid & 127, tp = tid >> 7;
    const float* vp = values + ((size_t)b * T_ + t0) * DV_ + cl * 4;
    float4 a = {0.f, 0.f, 0.f, 0.f};
#pragma unroll 4
    for (int t = tp; t < len; t += 2) {
        float4 v = *(const float4*)(vp + (size_t)t * DV_);
        float wt = wS[t];
        a.x += wt * v.x; a.y += wt * v.y; a.z += wt * v.z; a.w += wt * v.w;
    }
    if (tp == 1) ps[cl] = a;
    __syncthreads();
    if (tp == 0) {
        float4 o = ps[cl];
        o.x += a.x; o.y += a.y; o.z += a.z; o.w += a.w;
        *(float4*)(part + ((size_t)(b * P_ + p)) * DV_ + cl * 4) = o;
    }
}

// context phase 2: ctx[b,d] = sum_p partial[b,p,d]
__global__ void ctx2_kernel(const float* __restrict__ part, float* __restrict__ ctx) {
    int b = blockIdx.x, tid = threadIdx.x;   // 128 threads, float4 each
    const float* pp = part + (size_t)b * P_ * DV_ + tid * 4;
    float4 s = {0.f, 0.f, 0.f, 0.f};
#pragma unroll
    for (int p = 0; p < P_; ++p) {
        float4 v = *(const float4*)(pp + (size_t)p * DV_);
        s.x += v.x; s.y += v.y; s.z += v.z; s.w += v.w;
    }
    *(float4*)(ctx + (size_t)b * DV_ + tid * 4) = s;
}

extern "C" void kernel_launch(void* const* d_in, const int* in_sizes, int n_in,
                              void* d_out, int out_size, void* d_ws, size_t ws_size,
                              hipStream_t stream) {
    const float* query  = (const float*)d_in[0];
    const float* values = (const float*)d_in[1];
    const float* prev   = (const float*)d_in[2];
    const float* Wq     = (const float*)d_in[3];
    const float* bq     = (const float*)d_in[4];
    const float* Wm     = (const float*)d_in[5];
    const float* bm     = (const float*)d_in[6];
    const float* Wv     = (const float*)d_in[7];
    const float* bv     = (const float*)d_in[8];
    const float* Wc     = (const float*)d_in[9];
    const float* Wl     = (const float*)d_in[10];

    float* out  = (float*)d_out;
    float* ctx  = out;                 // [64,512]
    float* attw = out + B_ * DV_;      // [64,1000,1]

    char* ws = (char*)d_ws;
    float* qb     = (float*)(ws);                              // 32768 B
    float* scores = (float*)(ws + 32768);                      // 256000 B
    short* WmX    = (short*)(ws + 288768);                     // 131072 B
    short* WlX    = (short*)(ws + 419840);                     // 8192 B
    float* part   = (float*)(ws + 428032);                     // 2 MB

    prep_qb_kernel<<<73, 1024, 0, stream>>>(Wm, Wl, query, Wq, bq, bm, WmX, WlX, qb);
    score_kernel<<<500, 256, 0, stream>>>(values, prev, Wc, Wv, bv, WmX, WlX, qb, scores);
    softmax_kernel<<<B_, 256, 0, stream>>>(scores, attw);
    ctx1_kernel<<<dim3(B_, P_), 256, 0, stream>>>(values, attw, part);
    ctx2_kernel<<<B_, 128, 0, stream>>>(part, ctx);
}